// Round 1
// baseline (455.369 us; speedup 1.0000x reference)
//
#include <hip/hip_runtime.h>
#include <hip/hip_bf16.h>

// Problem constants
#define L  2048
#define D  32
#define DM 1024
#define H  16
#define DH 64
#define FF 4096

typedef unsigned short u16;
typedef __attribute__((ext_vector_type(8))) short bf16x8;   // MFMA A/B operand (8 bf16)
typedef __attribute__((ext_vector_type(4))) float f32x4;    // MFMA C/D operand
typedef __attribute__((ext_vector_type(4))) unsigned int u32x4;
typedef __attribute__((ext_vector_type(8))) unsigned short u16x8;
typedef __attribute__((ext_vector_type(4))) unsigned short u16x4;

static __device__ __forceinline__ float bf2f(u16 u) {
    return __uint_as_float(((unsigned)u) << 16);
}
static __device__ __forceinline__ u16 f2bf(float f) {
    union { __hip_bfloat16 b; u16 u; } cv;
    cv.b = __float2bfloat16(f);
    return cv.u;
}

// ---------------- conversion kernels ----------------
__global__ __launch_bounds__(256) void cvt_bf(const float* __restrict__ in,
                                              u16* __restrict__ out, int n4) {
    int i = blockIdx.x * 256 + threadIdx.x;
    if (i < n4) {
        const float4 v = reinterpret_cast<const float4*>(in)[i];
        u16x4 o = { f2bf(v.x), f2bf(v.y), f2bf(v.z), f2bf(v.w) };
        *reinterpret_cast<u16x4*>(out + (long)i * 4) = o;
    }
}

// out[c][r] = bf16(in[r][c]); in is R x C row-major. grid (C/32, R/32), block (32,8)
__global__ void cvt_T(const float* __restrict__ in, u16* __restrict__ out, int R, int C) {
    __shared__ float tile[32][33];
    const int tx = threadIdx.x, ty = threadIdx.y;
    const int bx = blockIdx.x * 32, by = blockIdx.y * 32;
    #pragma unroll
    for (int i = 0; i < 32; i += 8)
        tile[ty + i][tx] = in[(long)(by + ty + i) * C + bx + tx];
    __syncthreads();
    #pragma unroll
    for (int i = 0; i < 32; i += 8)
        out[(long)(bx + ty + i) * R + by + tx] = f2bf(tile[tx][ty + i]);
}

// ---------------- generic MFMA GEMM ----------------
// C[m][n] = sum_k A[m][k] * Bt[n][k] (+ bias[n])  -- Bt is B transposed (N x K row-major).
// 64x64 tile per 256-thread block (4 waves; wave w: rows w*16..w*16+15, 4 col-tiles).
// EPI: 0 = bf16 store, 1 = f32 store, 2 = exact gelu -> bf16 store.
// All of M, N multiples of 64; K multiple of 32 (no bounds checks).
#define LDT 40  // padded LDS pitch (elements) for a 32-wide K tile
template<int EPI>
__global__ __launch_bounds__(256) void gemm_bt(
    const u16* __restrict__ A, int lda, long aBS,
    const u16* __restrict__ Bt, int ldb, long bBS,
    void* __restrict__ Cv, int ldc, long cBS,
    const float* __restrict__ bias, int biasBS, int K)
{
    __shared__ u16 As[64 * LDT];
    __shared__ u16 Bs[64 * LDT];
    const int t = threadIdx.x;
    const int z = blockIdx.z;
    const int mBase = blockIdx.y * 64, nBase = blockIdx.x * 64;
    const u16* Ab = A + (long)z * aBS;
    const u16* Bb = Bt + (long)z * bBS;
    const int lane = t & 63, w = t >> 6;
    const int r = t >> 2, seg = t & 3;     // staging: row r (of 64), 8-elem segment seg (of 4)
    f32x4 acc[4] = { {0.f,0.f,0.f,0.f}, {0.f,0.f,0.f,0.f}, {0.f,0.f,0.f,0.f}, {0.f,0.f,0.f,0.f} };
    const long aRow = (long)(mBase + r) * lda;
    const long bRow = (long)(nBase + r) * ldb;
    for (int k0 = 0; k0 < K; k0 += 32) {
        __syncthreads();
        *reinterpret_cast<u32x4*>(&As[r * LDT + seg * 8]) =
            *reinterpret_cast<const u32x4*>(&Ab[aRow + k0 + seg * 8]);
        *reinterpret_cast<u32x4*>(&Bs[r * LDT + seg * 8]) =
            *reinterpret_cast<const u32x4*>(&Bb[bRow + k0 + seg * 8]);
        __syncthreads();
        const bf16x8 af = *reinterpret_cast<const bf16x8*>(
            &As[(w * 16 + (lane & 15)) * LDT + (lane >> 4) * 8]);
        #pragma unroll
        for (int j = 0; j < 4; ++j) {
            const bf16x8 bfr = *reinterpret_cast<const bf16x8*>(
                &Bs[(j * 16 + (lane & 15)) * LDT + (lane >> 4) * 8]);
            acc[j] = __builtin_amdgcn_mfma_f32_16x16x32_bf16(af, bfr, acc[j], 0, 0, 0);
        }
    }
    // Epilogue. Verified C/D layout: col = lane&15, row = (lane>>4)*4 + reg.
    const int rbase = mBase + w * 16 + ((lane >> 4) << 2);
    const int cb = nBase + (lane & 15);
    #pragma unroll
    for (int j = 0; j < 4; ++j) {
        const int col = cb + j * 16;
        const float badd = bias ? bias[(long)z * biasBS + col] : 0.f;
        #pragma unroll
        for (int i = 0; i < 4; ++i) {
            float v = acc[j][i] + badd;
            if (EPI == 2) v = 0.5f * v * (1.f + erff(v * 0.70710678118654752f));
            const long off = (long)z * cBS + (long)(rbase + i) * ldc + col;
            if (EPI == 1) reinterpret_cast<float*>(Cv)[off] = v;
            else          reinterpret_cast<u16*>(Cv)[off]  = f2bf(v);
        }
    }
}

// ---------------- fused attention core ----------------
// Per block: one position l. Computes scores[h,d] = (qk[l,h]·target[l,d] + q[l,h]·bk_h)/8
// + mask[l,d], softmax over d (32-lane shuffle groups), then tw[l,h,:] = sum_d p*target[l,d].
// target[l] staged in LDS as bf16 with XOR swizzle (m ^ ((d&15)<<3)) to break the
// 32-way bank conflict of the row-major [32][1024] tile. Exactly 64 KB LDS.
__global__ __launch_bounds__(512) void attn_fuse(
    const u16* __restrict__ qk, const u16* __restrict__ Q16,
    const float* __restrict__ target, const float* __restrict__ mask,
    const float* __restrict__ bk, u16* __restrict__ tw)
{
    __shared__ u16 tgtS[D * DM];
    const int l = blockIdx.x, t = threadIdx.x;

    const float* tl = target + (long)l * (D * DM);
    for (int i = t; i < (D * DM) / 4; i += 512) {
        const float4 v = reinterpret_cast<const float4*>(tl)[i];
        const int d = i >> 8;                 // (i*4) / 1024
        const int mm = (i & 255) * 4;
        const int cc = mm ^ ((d & 15) << 3);  // swizzle (element index, bits 3..6)
        u16x4 o = { f2bf(v.x), f2bf(v.y), f2bf(v.z), f2bf(v.w) };
        *reinterpret_cast<u16x4*>(&tgtS[d * DM + cc]) = o;
    }
    __syncthreads();

    const int h = t >> 5, g = t & 31;   // head, lane-in-group; g doubles as candidate d

    // q·bk_h term (group-reduced so every lane of the group holds it)
    float qb = bf2f(Q16[(long)l * DM + h * DH + g])      * bk[h * DH + g]
             + bf2f(Q16[(long)l * DM + h * DH + g + 32]) * bk[h * DH + g + 32];
    #pragma unroll
    for (int off = 16; off; off >>= 1) qb += __shfl_xor(qb, off, 32);

    // score for (h, d=g): dot(qk[l,h,:], target[l,g,:]) over DM
    const u16* qrow = qk + (long)l * (H * DM) + h * DM;   // broadcast within group -> L1
    const int sw = (g & 15) << 3;
    float s = 0.f;
    for (int m = 0; m < DM; m += 8) {
        const u16x8 qa = *reinterpret_cast<const u16x8*>(&qrow[m]);
        const u16x8 ta = *reinterpret_cast<const u16x8*>(&tgtS[g * DM + (m ^ sw)]);
        #pragma unroll
        for (int j = 0; j < 8; ++j) s += bf2f(qa[j]) * bf2f(ta[j]);
    }
    s = (s + qb) * 0.125f + mask[(long)l * D + g];

    // softmax across the 32-lane group (d dimension)
    float mx = s;
    #pragma unroll
    for (int off = 16; off; off >>= 1) mx = fmaxf(mx, __shfl_xor(mx, off, 32));
    const float e = __expf(s - mx);
    float sum = e;
    #pragma unroll
    for (int off = 16; off; off >>= 1) sum += __shfl_xor(sum, off, 32);
    const float p = e / sum;

    // weighted sum: this thread produces tw[l][h][g*32 .. g*32+32)
    const int mc = g * 32;
    float acc[32];
    #pragma unroll
    for (int j = 0; j < 32; ++j) acc[j] = 0.f;
    for (int d = 0; d < D; ++d) {
        const float pd = __shfl(p, d, 32);
        const int swd = (d & 15) << 3;
        #pragma unroll
        for (int m0 = 0; m0 < 32; m0 += 8) {
            const u16x8 v = *reinterpret_cast<const u16x8*>(&tgtS[d * DM + ((mc + m0) ^ swd)]);
            #pragma unroll
            for (int j = 0; j < 8; ++j) acc[m0 + j] += pd * bf2f(v[j]);
        }
    }
    u16* dst = tw + (long)l * (H * DM) + h * DM + mc;
    #pragma unroll
    for (int m0 = 0; m0 < 32; m0 += 8) {
        u16x8 o;
        #pragma unroll
        for (int j = 0; j < 8; ++j) o[j] = f2bf(acc[m0 + j]);
        *reinterpret_cast<u16x8*>(&dst[m0]) = o;
    }
}

// ---------------- fused residual-add + LayerNorm ----------------
// out = LN(a + b) * g + be. One block per row. Optional bf16 copy (o16).
__global__ __launch_bounds__(256) void ln_fuse(
    const float* __restrict__ a, const float* __restrict__ b,
    const float* __restrict__ g, const float* __restrict__ be,
    float* __restrict__ o32, u16* __restrict__ o16)
{
    const int l = blockIdx.x, t = threadIdx.x;
    __shared__ float S[4], SS[4];
    __shared__ float stats[2];
    const float4 va = reinterpret_cast<const float4*>(a + (long)l * DM)[t];
    const float4 vb = reinterpret_cast<const float4*>(b + (long)l * DM)[t];
    float v[4] = { va.x + vb.x, va.y + vb.y, va.z + vb.z, va.w + vb.w };
    float s  = v[0] + v[1] + v[2] + v[3];
    float ss = v[0]*v[0] + v[1]*v[1] + v[2]*v[2] + v[3]*v[3];
    #pragma unroll
    for (int off = 32; off; off >>= 1) { s += __shfl_down(s, off); ss += __shfl_down(ss, off); }
    if ((t & 63) == 0) { S[t >> 6] = s; SS[t >> 6] = ss; }
    __syncthreads();
    if (t == 0) {
        const float St  = S[0] + S[1] + S[2] + S[3];
        const float SSt = SS[0] + SS[1] + SS[2] + SS[3];
        const float mu  = St * (1.f / DM);
        const float var = fmaxf(SSt * (1.f / DM) - mu * mu, 0.f);
        stats[0] = mu;
        stats[1] = rsqrtf(var + 1e-5f);
    }
    __syncthreads();
    const float mu = stats[0], rs = stats[1];
    const int c0 = t * 4;
    float ov[4];
    #pragma unroll
    for (int j = 0; j < 4; ++j) ov[j] = (v[j] - mu) * rs * g[c0 + j] + be[c0 + j];
    float4 o; o.x = ov[0]; o.y = ov[1]; o.z = ov[2]; o.w = ov[3];
    reinterpret_cast<float4*>(o32 + (long)l * DM)[t] = o;
    if (o16) {
        u16x4 q = { f2bf(ov[0]), f2bf(ov[1]), f2bf(ov[2]), f2bf(ov[3]) };
        *reinterpret_cast<u16x4*>(o16 + (long)l * DM + c0) = q;
    }
}

// ---------------- launcher ----------------
extern "C" void kernel_launch(void* const* d_in, const int* in_sizes, int n_in,
                              void* d_out, int out_size, void* d_ws, size_t ws_size,
                              hipStream_t stream)
{
    const float* src    = (const float*)d_in[0];
    const float* target = (const float*)d_in[1];
    const float* amask  = (const float*)d_in[2];
    const float* Wq = (const float*)d_in[3];
    const float* bq = (const float*)d_in[4];
    const float* Wk = (const float*)d_in[5];
    const float* bk = (const float*)d_in[6];
    const float* Wv = (const float*)d_in[7];
    const float* bv = (const float*)d_in[8];
    const float* W1 = (const float*)d_in[9];
    const float* b1 = (const float*)d_in[10];
    const float* W2 = (const float*)d_in[11];
    const float* b2 = (const float*)d_in[12];
    const float* g1  = (const float*)d_in[13];
    const float* be1 = (const float*)d_in[14];
    const float* g2  = (const float*)d_in[15];
    const float* be2 = (const float*)d_in[16];

    // Workspace arena (peak 158 MB). The 64 MB qk region is dead after attn_fuse
    // and is re-used (time-disjoint) for Y16/Z32/ctx32/x32/x16.
    char* ws = (char*)d_ws;
    const size_t MB = (size_t)1 << 20;
    u16*   src16 = (u16*)  (ws +  0 * MB);  //  4 MB  bf16(src)
    u16*   Wk16  = (u16*)  (ws +  4 * MB);  //  2 MB  bf16(Wk)        (Bt for qk-transform)
    u16*   WqT   = (u16*)  (ws +  6 * MB);  //  2 MB  bf16(Wq^T)
    u16*   WvT   = (u16*)  (ws +  8 * MB);  //  2 MB  bf16(Wv^T)
    u16*   W1T   = (u16*)  (ws + 10 * MB);  //  8 MB  bf16(W1^T)
    u16*   W2T   = (u16*)  (ws + 18 * MB);  //  8 MB  bf16(W2^T)
    u16*   Q16   = (u16*)  (ws + 26 * MB);  //  4 MB  q = src@Wq+bq
    u16*   qk16  = (u16*)  (ws + 30 * MB);  // 64 MB  qk[l,h,m]
    u16*   Y16   = (u16*)  (ws + 30 * MB);  // 16 MB  gelu(x@W1+b1)   [aliases dead qk]
    float* Z32   = (float*)(ws + 46 * MB);  //  8 MB  Y@W2+b2         [aliases dead qk]
    float* ctx32 = (float*)(ws + 54 * MB);  //  8 MB  attention ctx   [aliases dead qk]
    float* x32   = (float*)(ws + 62 * MB);  //  8 MB  LN1 out         [aliases dead qk]
    u16*   x16   = (u16*)  (ws + 70 * MB);  //  4 MB  bf16(x)         [aliases dead qk]
    u16*   tw16  = (u16*)  (ws + 94 * MB);  // 64 MB  softmax-weighted target sums

    // dtype conversions / transposes
    cvt_bf<<<2048, 256, 0, stream>>>(src, src16, (L * DM) / 4);
    cvt_bf<<<1024, 256, 0, stream>>>(Wk, Wk16, (DM * DM) / 4);
    dim3 tb(32, 8);
    cvt_T<<<dim3(32, 32),  tb, 0, stream>>>(Wq, WqT, DM, DM);
    cvt_T<<<dim3(32, 32),  tb, 0, stream>>>(Wv, WvT, DM, DM);
    cvt_T<<<dim3(128, 32), tb, 0, stream>>>(W1, W1T, DM, FF);
    cvt_T<<<dim3(32, 128), tb, 0, stream>>>(W2, W2T, FF, DM);

    // G1: Q = bf16(src @ Wq + bq)                       M=2048 N=1024 K=1024
    gemm_bt<0><<<dim3(DM / 64, L / 64, 1), 256, 0, stream>>>(
        src16, DM, 0, WqT, DM, 0, Q16, DM, 0, bq, 0, DM);
    // G2 (batched over heads): qk[l,h,c] = sum_t Q[l,h,t] * Wk[c, h*64+t]   K=64
    gemm_bt<0><<<dim3(DM / 64, L / 64, H), 256, 0, stream>>>(
        Q16, DM, DH, Wk16, DM, DH, qk16, H * DM, DM, nullptr, 0, DH);
    // fused scores -> softmax -> weighted target sums
    attn_fuse<<<L, 512, 0, stream>>>(qk16, Q16, target, amask, bk, tw16);
    // G3 (batched over heads): ctx[l, h*64+j] = sum_m tw[l,h,m] * Wv[m, h*64+j] + bv
    gemm_bt<1><<<dim3(1, L / 64, H), 256, 0, stream>>>(
        tw16, H * DM, DM, WvT, DM, (long)DH * DM, ctx32, DM, DH, bv, DH, DM);
    // x = LN(src + ctx)
    ln_fuse<<<L, 256, 0, stream>>>(src, ctx32, g1, be1, x32, x16);
    // G4: Y = bf16(gelu(x @ W1 + b1))                   M=2048 N=4096 K=1024
    gemm_bt<2><<<dim3(FF / 64, L / 64, 1), 256, 0, stream>>>(
        x16, DM, 0, W1T, DM, 0, Y16, FF, 0, b1, 0, DM);
    // G5: Z = Y @ W2 + b2 (f32)                         M=2048 N=1024 K=4096
    gemm_bt<1><<<dim3(DM / 64, L / 64, 1), 256, 0, stream>>>(
        Y16, FF, 0, W2T, FF, 0, Z32, DM, 0, b2, 0, FF);
    // out = LN(x + Z)
    ln_fuse<<<L, 256, 0, stream>>>(x32, Z32, g2, be2, (float*)d_out, nullptr);
}

// Round 5
// 360.543 us; speedup vs baseline: 1.2630x; 1.2630x over previous
//
#include <hip/hip_runtime.h>
#include <hip/hip_bf16.h>

// Problem constants
#define L  2048
#define D  32
#define DM 1024
#define H  16
#define DH 64
#define FF 4096

typedef unsigned short u16;
typedef __attribute__((ext_vector_type(8))) short bf16x8;   // MFMA A/B operand (8 bf16)
typedef __attribute__((ext_vector_type(4))) float f32x4;    // MFMA C/D operand
typedef __attribute__((ext_vector_type(4))) unsigned int u32x4;
typedef __attribute__((ext_vector_type(8))) unsigned short u16x8;
typedef __attribute__((ext_vector_type(4))) unsigned short u16x4;

static __device__ __forceinline__ float bf2f(u16 u) {
    return __uint_as_float(((unsigned)u) << 16);
}
static __device__ __forceinline__ u16 f2bf(float f) {
    union { __hip_bfloat16 b; u16 u; } cv;
    cv.b = __float2bfloat16(f);
    return cv.u;
}

// ---------------- conversion kernels ----------------
__global__ __launch_bounds__(256) void cvt_bf(const float* __restrict__ in,
                                              u16* __restrict__ out, int n4) {
    int i = blockIdx.x * 256 + threadIdx.x;
    if (i < n4) {
        const float4 v = reinterpret_cast<const float4*>(in)[i];
        u16x4 o = { f2bf(v.x), f2bf(v.y), f2bf(v.z), f2bf(v.w) };
        *reinterpret_cast<u16x4*>(out + (long)i * 4) = o;
    }
}

// out[c][r] = bf16(in[r][c]); in is R x C row-major. grid (C/32, R/32), block (32,8)
__global__ void cvt_T(const float* __restrict__ in, u16* __restrict__ out, int R, int C) {
    __shared__ float tile[32][33];
    const int tx = threadIdx.x, ty = threadIdx.y;
    const int bx = blockIdx.x * 32, by = blockIdx.y * 32;
    #pragma unroll
    for (int i = 0; i < 32; i += 8)
        tile[ty + i][tx] = in[(long)(by + ty + i) * C + bx + tx];
    __syncthreads();
    #pragma unroll
    for (int i = 0; i < 32; i += 8)
        out[(long)(bx + ty + i) * R + by + tx] = f2bf(tile[tx][ty + i]);
}

// ---------------- generic MFMA GEMM ----------------
// C[m][n] = sum_k A[m][k] * Bt[n][k] (+ bias[n])  -- Bt is B transposed (N x K row-major).
// 64x64 tile per 256-thread block (4 waves; wave w: rows w*16..w*16+15, 4 col-tiles).
// EPI: 0 = bf16 store, 1 = f32 store, 2 = exact gelu -> bf16 store.
#define LDT 40  // padded LDS pitch (elements) for a 32-wide K tile
template<int EPI>
__global__ __launch_bounds__(256) void gemm_bt(
    const u16* __restrict__ A, int lda, long aBS,
    const u16* __restrict__ Bt, int ldb, long bBS,
    void* __restrict__ Cv, int ldc, long cBS,
    const float* __restrict__ bias, int biasBS, int K)
{
    __shared__ u16 As[64 * LDT];
    __shared__ u16 Bs[64 * LDT];
    const int t = threadIdx.x;
    const int z = blockIdx.z;
    const int mBase = blockIdx.y * 64, nBase = blockIdx.x * 64;
    const u16* Ab = A + (long)z * aBS;
    const u16* Bb = Bt + (long)z * bBS;
    const int lane = t & 63, w = t >> 6;
    const int r = t >> 2, seg = t & 3;
    f32x4 acc[4] = { {0.f,0.f,0.f,0.f}, {0.f,0.f,0.f,0.f}, {0.f,0.f,0.f,0.f}, {0.f,0.f,0.f,0.f} };
    const long aRow = (long)(mBase + r) * lda;
    const long bRow = (long)(nBase + r) * ldb;
    for (int k0 = 0; k0 < K; k0 += 32) {
        __syncthreads();
        *reinterpret_cast<u32x4*>(&As[r * LDT + seg * 8]) =
            *reinterpret_cast<const u32x4*>(&Ab[aRow + k0 + seg * 8]);
        *reinterpret_cast<u32x4*>(&Bs[r * LDT + seg * 8]) =
            *reinterpret_cast<const u32x4*>(&Bb[bRow + k0 + seg * 8]);
        __syncthreads();
        const bf16x8 af = *reinterpret_cast<const bf16x8*>(
            &As[(w * 16 + (lane & 15)) * LDT + (lane >> 4) * 8]);
        #pragma unroll
        for (int j = 0; j < 4; ++j) {
            const bf16x8 bfr = *reinterpret_cast<const bf16x8*>(
                &Bs[(j * 16 + (lane & 15)) * LDT + (lane >> 4) * 8]);
            acc[j] = __builtin_amdgcn_mfma_f32_16x16x32_bf16(af, bfr, acc[j], 0, 0, 0);
        }
    }
    const int rbase = mBase + w * 16 + ((lane >> 4) << 2);
    const int cb = nBase + (lane & 15);
    #pragma unroll
    for (int j = 0; j < 4; ++j) {
        const int col = cb + j * 16;
        const float badd = bias ? bias[(long)z * biasBS + col] : 0.f;
        #pragma unroll
        for (int i = 0; i < 4; ++i) {
            float v = acc[j][i] + badd;
            if (EPI == 2) v = 0.5f * v * (1.f + erff(v * 0.70710678118654752f));
            const long off = (long)z * cBS + (long)(rbase + i) * ldc + col;
            if (EPI == 1) reinterpret_cast<float*>(Cv)[off] = v;
            else          reinterpret_cast<u16*>(Cv)[off]  = f2bf(v);
        }
    }
}

// ---------------- fused attention core (MFMA, no exotic mechanisms) ----------------
// One block per position l, 512 threads (8 waves). Static LDS = 64 KB.
// LDS layout: PROVEN in round 1 (attn_fuse passed): tgtS row-major [32][1024] bf16
// with element XOR swizzle m_sw = m ^ ((d&15)<<3).
// Phase 1 (QK): every wave redundantly computes full scores[d,h] =
//   sum_m tgt[d,m]*qk[h,m] over K=1024 using the PROVEN gemm_bt fragment pattern
//   (A row = lane&15, 8 contiguous k at (lane>>4)*8; B identical).
//   C layout (verified): lane (g=lane>>4, hm=lane&15) holds h=hm,
//   d = 4g+r (acc0) / 16+4g+r (acc1).
// Phase 2: softmax over d in-register; reduce over the 4 g-lanes of each h via
//   shfl_xor 16/32. The q.bk score term is constant over d -> cancels -> dropped.
//   P slots: pf[j] = P[h][d_map(g,j)], d_map(g,j) = 16*(j>=4) + 4g + (j&3).
// Phase 3 (PV): tw[h,m] = sum_d P[h,d]*tgt[d,m] via mfma(A=tgt^T, B=P).
//   A-fragment: 8 plain scalar LDS reads: slot j = tgt[d_map(g,j)][m=mg*16+hm].
//   A and B carry the SAME d-permutation per (g,j) -> contraction is
//   sum_d tgt[d][m]*P[h][d] exactly (slot->k map is identical for A and B,
//   as proven by gemm_bt passing). Output: lane holds h=hm, m=mg*16+4g+r
//   -> coalesced b64 store into tw[l][h][m].
__global__ __launch_bounds__(512) void attn_mfma(
    const u16* __restrict__ qk,        // [L][H][DM] bf16
    const float* __restrict__ target,  // [L][D][DM] f32
    const float* __restrict__ mask,    // [L][D]     f32
    u16* __restrict__ tw)              // [L][H][DM] bf16
{
    __shared__ u16 tgtS[D * DM];                 // 64 KB

    const int l = blockIdx.x, t = threadIdx.x;
    const int lane = t & 63, w = t >> 6;
    const int g = lane >> 4, hm = lane & 15;

    // ---- stage target[l] -> bf16 swizzled LDS (verbatim from round-1 PASSING kernel) ----
    const float* tl = target + (long)l * (D * DM);
    for (int i = t; i < (D * DM) / 4; i += 512) {
        const float4 v = reinterpret_cast<const float4*>(tl)[i];
        const int d = i >> 8;                 // (i*4) / 1024
        const int mm = (i & 255) * 4;
        const int cc = mm ^ ((d & 15) << 3);  // swizzle (element index, bits 3..6)
        u16x4 o = { f2bf(v.x), f2bf(v.y), f2bf(v.z), f2bf(v.w) };
        *reinterpret_cast<u16x4*>(&tgtS[d * DM + cc]) = o;
    }
    __syncthreads();

    // ---- QK: full-K scores, computed redundantly per wave ----
    f32x4 acc0 = {0.f, 0.f, 0.f, 0.f}, acc1 = {0.f, 0.f, 0.f, 0.f};
    const u16* qrow = qk + (long)l * (H * DM) + hm * DM;   // B rows: h = hm
    const int swz = hm << 3;                               // (d&15)<<3 for d=hm and d=16+hm
    for (int ks = 0; ks < 32; ++ks) {
        const int mcol = ks * 32 + g * 8;                  // 8 contiguous k at g*8 (proven map)
        const bf16x8 yf = *reinterpret_cast<const bf16x8*>(&qrow[mcol]);
        const bf16x8 x0 = *reinterpret_cast<const bf16x8*>(&tgtS[hm * DM + (mcol ^ swz)]);
        const bf16x8 x1 = *reinterpret_cast<const bf16x8*>(&tgtS[(16 + hm) * DM + (mcol ^ swz)]);
        acc0 = __builtin_amdgcn_mfma_f32_16x16x32_bf16(x0, yf, acc0, 0, 0, 0);
        acc1 = __builtin_amdgcn_mfma_f32_16x16x32_bf16(x1, yf, acc1, 0, 0, 0);
    }

    // ---- softmax over d (lane holds d = {4g+r, 16+4g+r} for h = hm) ----
    const float* mrow = mask + (long)l * D;
    float sc[8];
    #pragma unroll
    for (int r = 0; r < 4; ++r) {
        sc[r]     = acc0[r] * 0.125f + mrow[4 * g + r];
        sc[4 + r] = acc1[r] * 0.125f + mrow[16 + 4 * g + r];
    }
    float mx = sc[0];
    #pragma unroll
    for (int r = 1; r < 8; ++r) mx = fmaxf(mx, sc[r]);
    mx = fmaxf(mx, __shfl_xor(mx, 16));
    mx = fmaxf(mx, __shfl_xor(mx, 32));
    float sum = 0.f;
    #pragma unroll
    for (int r = 0; r < 8; ++r) { sc[r] = __expf(sc[r] - mx); sum += sc[r]; }
    sum += __shfl_xor(sum, 16);
    sum += __shfl_xor(sum, 32);
    const float pinv = 1.0f / sum;
    bf16x8 pf;
    #pragma unroll
    for (int r = 0; r < 8; ++r) pf[r] = (short)f2bf(sc[r] * pinv);

    // ---- PV: 8 m-tiles per wave; A = tgt^T via plain scalar LDS reads, B = P ----
    u16* twl = tw + (long)l * (H * DM);
    const f32x4 zero = {0.f, 0.f, 0.f, 0.f};
    #pragma unroll
    for (int i = 0; i < 8; ++i) {
        const int mg = w * 8 + i;
        const int m = mg * 16 + hm;
        bf16x8 af;
        #pragma unroll
        for (int j = 0; j < 4; ++j) {
            const int d0 = 4 * g + j;          // d_map slots 0..3 (d < 16)
            const int d1 = 16 + 4 * g + j;     // d_map slots 4..7 (d1&15 = d0)
            af[j]     = (short)tgtS[d0 * DM + (m ^ (d0 << 3))];
            af[4 + j] = (short)tgtS[d1 * DM + (m ^ (d0 << 3))];
        }
        const f32x4 c = __builtin_amdgcn_mfma_f32_16x16x32_bf16(af, pf, zero, 0, 0, 0);
        u16x4 o = { f2bf(c[0]), f2bf(c[1]), f2bf(c[2]), f2bf(c[3]) };
        *reinterpret_cast<u16x4*>(&twl[hm * DM + mg * 16 + 4 * g]) = o;
    }
}

// ---------------- fused residual-add + LayerNorm ----------------
__global__ __launch_bounds__(256) void ln_fuse(
    const float* __restrict__ a, const float* __restrict__ b,
    const float* __restrict__ g, const float* __restrict__ be,
    float* __restrict__ o32, u16* __restrict__ o16)
{
    const int l = blockIdx.x, t = threadIdx.x;
    __shared__ float S[4], SS[4];
    __shared__ float stats[2];
    const float4 va = reinterpret_cast<const float4*>(a + (long)l * DM)[t];
    const float4 vb = reinterpret_cast<const float4*>(b + (long)l * DM)[t];
    float v[4] = { va.x + vb.x, va.y + vb.y, va.z + vb.z, va.w + vb.w };
    float s  = v[0] + v[1] + v[2] + v[3];
    float ss = v[0]*v[0] + v[1]*v[1] + v[2]*v[2] + v[3]*v[3];
    #pragma unroll
    for (int off = 32; off; off >>= 1) { s += __shfl_down(s, off); ss += __shfl_down(ss, off); }
    if ((t & 63) == 0) { S[t >> 6] = s; SS[t >> 6] = ss; }
    __syncthreads();
    if (t == 0) {
        const float St  = S[0] + S[1] + S[2] + S[3];
        const float SSt = SS[0] + SS[1] + SS[2] + SS[3];
        const float mu  = St * (1.f / DM);
        const float var = fmaxf(SSt * (1.f / DM) - mu * mu, 0.f);
        stats[0] = mu;
        stats[1] = rsqrtf(var + 1e-5f);
    }
    __syncthreads();
    const float mu = stats[0], rs = stats[1];
    const int c0 = t * 4;
    float ov[4];
    #pragma unroll
    for (int j = 0; j < 4; ++j) ov[j] = (v[j] - mu) * rs * g[c0 + j] + be[c0 + j];
    float4 o; o.x = ov[0]; o.y = ov[1]; o.z = ov[2]; o.w = ov[3];
    reinterpret_cast<float4*>(o32 + (long)l * DM)[t] = o;
    if (o16) {
        u16x4 q = { f2bf(ov[0]), f2bf(ov[1]), f2bf(ov[2]), f2bf(ov[3]) };
        *reinterpret_cast<u16x4*>(o16 + (long)l * DM + c0) = q;
    }
}

// ---------------- launcher ----------------
extern "C" void kernel_launch(void* const* d_in, const int* in_sizes, int n_in,
                              void* d_out, int out_size, void* d_ws, size_t ws_size,
                              hipStream_t stream)
{
    const float* src    = (const float*)d_in[0];
    const float* target = (const float*)d_in[1];
    const float* amask  = (const float*)d_in[2];
    const float* Wq = (const float*)d_in[3];
    const float* bq = (const float*)d_in[4];
    const float* Wk = (const float*)d_in[5];
    const float* Wv = (const float*)d_in[7];
    const float* bv = (const float*)d_in[8];
    const float* W1 = (const float*)d_in[9];
    const float* b1 = (const float*)d_in[10];
    const float* W2 = (const float*)d_in[11];
    const float* b2 = (const float*)d_in[12];
    const float* g1  = (const float*)d_in[13];
    const float* be1 = (const float*)d_in[14];
    const float* g2  = (const float*)d_in[15];
    const float* be2 = (const float*)d_in[16];

    // Workspace arena (peak 158 MB). qk region is dead after attn and re-used.
    char* ws = (char*)d_ws;
    const size_t MB = (size_t)1 << 20;
    u16*   src16 = (u16*)  (ws +  0 * MB);  //  4 MB  bf16(src)
    u16*   Wk16  = (u16*)  (ws +  4 * MB);  //  2 MB  bf16(Wk)
    u16*   WqT   = (u16*)  (ws +  6 * MB);  //  2 MB  bf16(Wq^T)
    u16*   WvT   = (u16*)  (ws +  8 * MB);  //  2 MB  bf16(Wv^T)
    u16*   W1T   = (u16*)  (ws + 10 * MB);  //  8 MB  bf16(W1^T)
    u16*   W2T   = (u16*)  (ws + 18 * MB);  //  8 MB  bf16(W2^T)
    u16*   Q16   = (u16*)  (ws + 26 * MB);  //  4 MB  q = src@Wq+bq
    u16*   qk16  = (u16*)  (ws + 30 * MB);  // 64 MB  qk[l,h,m]
    u16*   Y16   = (u16*)  (ws + 30 * MB);  // 16 MB  gelu(x@W1+b1)   [aliases dead qk]
    float* Z32   = (float*)(ws + 46 * MB);  //  8 MB  Y@W2+b2         [aliases dead qk]
    float* ctx32 = (float*)(ws + 54 * MB);  //  8 MB  attention ctx   [aliases dead qk]
    float* x32   = (float*)(ws + 62 * MB);  //  8 MB  LN1 out         [aliases dead qk]
    u16*   x16   = (u16*)  (ws + 70 * MB);  //  4 MB  bf16(x)         [aliases dead qk]
    u16*   tw16  = (u16*)  (ws + 94 * MB);  // 64 MB  softmax-weighted target sums

    cvt_bf<<<2048, 256, 0, stream>>>(src, src16, (L * DM) / 4);
    cvt_bf<<<1024, 256, 0, stream>>>(Wk, Wk16, (DM * DM) / 4);
    dim3 tb(32, 8);
    cvt_T<<<dim3(32, 32),  tb, 0, stream>>>(Wq, WqT, DM, DM);
    cvt_T<<<dim3(32, 32),  tb, 0, stream>>>(Wv, WvT, DM, DM);
    cvt_T<<<dim3(128, 32), tb, 0, stream>>>(W1, W1T, DM, FF);
    cvt_T<<<dim3(32, 128), tb, 0, stream>>>(W2, W2T, FF, DM);

    // G1: Q = bf16(src @ Wq + bq)
    gemm_bt<0><<<dim3(DM / 64, L / 64, 1), 256, 0, stream>>>(
        src16, DM, 0, WqT, DM, 0, Q16, DM, 0, bq, 0, DM);
    // G2 (batched over heads): qk[l,h,c] = sum_t Q[l,h,t] * Wk[c, h*64+t]
    gemm_bt<0><<<dim3(DM / 64, L / 64, H), 256, 0, stream>>>(
        Q16, DM, DH, Wk16, DM, DH, qk16, H * DM, DM, nullptr, 0, DH);
    // fused MFMA attention: scores -> softmax -> weighted target sums
    attn_mfma<<<L, 512, 0, stream>>>(qk16, target, amask, tw16);
    // G3 (batched over heads): ctx[l, h*64+j] = sum_m tw[l,h,m] * Wv[m, h*64+j] + bv
    gemm_bt<1><<<dim3(1, L / 64, H), 256, 0, stream>>>(
        tw16, H * DM, DM, WvT, DM, (long)DH * DM, ctx32, DM, DH, bv, DH, DM);
    // x = LN(src + ctx)
    ln_fuse<<<L, 256, 0, stream>>>(src, ctx32, g1, be1, x32, x16);
    // G4: Y = bf16(gelu(x @ W1 + b1))
    gemm_bt<2><<<dim3(FF / 64, L / 64, 1), 256, 0, stream>>>(
        x16, DM, 0, W1T, DM, 0, Y16, FF, 0, b1, 0, DM);
    // G5: Z = Y @ W2 + b2 (f32)
    gemm_bt<1><<<dim3(DM / 64, L / 64, 1), 256, 0, stream>>>(
        Y16, FF, 0, W2T, FF, 0, Z32, DM, 0, b2, 0, FF);
    // out = LN(x + Z)
    ln_fuse<<<L, 256, 0, stream>>>(x32, Z32, g2, be2, (float*)d_out, nullptr);
}

// Round 7
// 298.563 us; speedup vs baseline: 1.5252x; 1.2076x over previous
//
#include <hip/hip_runtime.h>
#include <hip/hip_bf16.h>

// Problem constants
#define L  2048
#define D  32
#define DM 1024
#define H  16
#define DH 64
#define FF 4096

typedef unsigned short u16;
typedef __attribute__((ext_vector_type(8))) short bf16x8;   // MFMA A/B operand (8 bf16)
typedef __attribute__((ext_vector_type(4))) float f32x4;    // MFMA C/D operand
typedef __attribute__((ext_vector_type(4))) unsigned int u32x4;
typedef __attribute__((ext_vector_type(8))) unsigned short u16x8;
typedef __attribute__((ext_vector_type(4))) unsigned short u16x4;

static __device__ __forceinline__ float bf2f(u16 u) {
    return __uint_as_float(((unsigned)u) << 16);
}
static __device__ __forceinline__ u16 f2bf(float f) {
    union { __hip_bfloat16 b; u16 u; } cv;
    cv.b = __float2bfloat16(f);
    return cv.u;
}
// async global->LDS, 16B per lane. LDS dest must be wave-uniform base + lane*16.
static __device__ __forceinline__ void gll16(const u16* gsrc, u16* ldst) {
    __builtin_amdgcn_global_load_lds(
        (const __attribute__((address_space(1))) unsigned int*)gsrc,
        (__attribute__((address_space(3))) unsigned int*)ldst, 16, 0, 0);
}

// ---------------- conversion kernels ----------------
__global__ __launch_bounds__(256) void cvt_bf(const float* __restrict__ in,
                                              u16* __restrict__ out, int n4) {
    int i = blockIdx.x * 256 + threadIdx.x;
    if (i < n4) {
        const float4 v = reinterpret_cast<const float4*>(in)[i];
        u16x4 o = { f2bf(v.x), f2bf(v.y), f2bf(v.z), f2bf(v.w) };
        *reinterpret_cast<u16x4*>(out + (long)i * 4) = o;
    }
}

// out[c][r] = bf16(in[r][c]); in is R x C row-major. grid (C/32, R/32), block (32,8)
__global__ void cvt_T(const float* __restrict__ in, u16* __restrict__ out, int R, int C) {
    __shared__ float tile[32][33];
    const int tx = threadIdx.x, ty = threadIdx.y;
    const int bx = blockIdx.x * 32, by = blockIdx.y * 32;
    #pragma unroll
    for (int i = 0; i < 32; i += 8)
        tile[ty + i][tx] = in[(long)(by + ty + i) * C + bx + tx];
    __syncthreads();
    #pragma unroll
    for (int i = 0; i < 32; i += 8)
        out[(long)(bx + ty + i) * R + by + tx] = f2bf(tile[tx][ty + i]);
}

// ---------------- generic MFMA GEMM (64x64 tile; kept for G1/G2/G3) ----------------
#define LDT 40
template<int EPI>
__global__ __launch_bounds__(256) void gemm_bt(
    const u16* __restrict__ A, int lda, long aBS,
    const u16* __restrict__ Bt, int ldb, long bBS,
    void* __restrict__ Cv, int ldc, long cBS,
    const float* __restrict__ bias, int biasBS, int K)
{
    __shared__ u16 As[64 * LDT];
    __shared__ u16 Bs[64 * LDT];
    const int t = threadIdx.x;
    const int z = blockIdx.z;
    const int mBase = blockIdx.y * 64, nBase = blockIdx.x * 64;
    const u16* Ab = A + (long)z * aBS;
    const u16* Bb = Bt + (long)z * bBS;
    const int lane = t & 63, w = t >> 6;
    const int r = t >> 2, seg = t & 3;
    f32x4 acc[4] = { {0.f,0.f,0.f,0.f}, {0.f,0.f,0.f,0.f}, {0.f,0.f,0.f,0.f}, {0.f,0.f,0.f,0.f} };
    const long aRow = (long)(mBase + r) * lda;
    const long bRow = (long)(nBase + r) * ldb;
    for (int k0 = 0; k0 < K; k0 += 32) {
        __syncthreads();
        *reinterpret_cast<u32x4*>(&As[r * LDT + seg * 8]) =
            *reinterpret_cast<const u32x4*>(&Ab[aRow + k0 + seg * 8]);
        *reinterpret_cast<u32x4*>(&Bs[r * LDT + seg * 8]) =
            *reinterpret_cast<const u32x4*>(&Bb[bRow + k0 + seg * 8]);
        __syncthreads();
        const bf16x8 af = *reinterpret_cast<const bf16x8*>(
            &As[(w * 16 + (lane & 15)) * LDT + (lane >> 4) * 8]);
        #pragma unroll
        for (int j = 0; j < 4; ++j) {
            const bf16x8 bfr = *reinterpret_cast<const bf16x8*>(
                &Bs[(j * 16 + (lane & 15)) * LDT + (lane >> 4) * 8]);
            acc[j] = __builtin_amdgcn_mfma_f32_16x16x32_bf16(af, bfr, acc[j], 0, 0, 0);
        }
    }
    const int rbase = mBase + w * 16 + ((lane >> 4) << 2);
    const int cb = nBase + (lane & 15);
    #pragma unroll
    for (int j = 0; j < 4; ++j) {
        const int col = cb + j * 16;
        const float badd = bias ? bias[(long)z * biasBS + col] : 0.f;
        #pragma unroll
        for (int i = 0; i < 4; ++i) {
            float v = acc[j][i] + badd;
            if (EPI == 2) v = 0.5f * v * (1.f + erff(v * 0.70710678118654752f));
            const long off = (long)z * cBS + (long)(rbase + i) * ldc + col;
            if (EPI == 1) reinterpret_cast<float*>(Cv)[off] = v;
            else          reinterpret_cast<u16*>(Cv)[off]  = f2bf(v);
        }
    }
}

// ---------------- 128x128-tile MFMA GEMM (m97 structure) for G4/G5 ----------------
// 256 threads = 4 waves in 2x2; per-wave 64x64 (acc[4][4]). BK=64.
// Staging via global_load_lds width=16, linear LDS dest; bank conflicts broken by a
// two-sided granule XOR swizzle (rule #21): LDS[r][g] holds source granule g^(r&7);
// ds_read applies the same XOR. 32 KB LDS, 2 barriers per K-step.
template<int EPI>
__global__ __launch_bounds__(256) void gemm128(
    const u16* __restrict__ A, int lda, long aZ,
    const u16* __restrict__ Bt, int ldb, long bZ,
    void* __restrict__ Cv, int ldc, long cZ,
    const float* __restrict__ bias, int K)
{
    __shared__ u16 As[128 * 64];
    __shared__ u16 Bs[128 * 64];
    const int t = threadIdx.x, lane = t & 63, w = t >> 6;
    const int z = blockIdx.z;
    const int mBase = blockIdx.y * 128, nBase = blockIdx.x * 128;
    const u16* Ab = A + (long)z * aZ;
    const u16* Bb = Bt + (long)z * bZ;
    const int wr = w >> 1, wc = w & 1;
    const int sr = lane >> 3, sg = lane & 7, sswz = sg ^ sr;   // staging row-in-8 / granule
    f32x4 acc[4][4];
    #pragma unroll
    for (int mi = 0; mi < 4; ++mi)
        #pragma unroll
        for (int ni = 0; ni < 4; ++ni) acc[mi][ni] = (f32x4){0.f, 0.f, 0.f, 0.f};

    for (int k0 = 0; k0 < K; k0 += 64) {
        #pragma unroll
        for (int i = 0; i < 4; ++i) {
            const int r = w * 32 + i * 8 + sr;                 // r&7 == sr
            gll16(&Ab[(long)(mBase + r) * lda + k0 + sswz * 8], &As[r * 64 + sg * 8]);
        }
        #pragma unroll
        for (int i = 0; i < 4; ++i) {
            const int r = w * 32 + i * 8 + sr;
            gll16(&Bb[(long)(nBase + r) * ldb + k0 + sswz * 8], &Bs[r * 64 + sg * 8]);
        }
        __syncthreads();   // drains vmcnt -> tiles ready
        #pragma unroll
        for (int ks = 0; ks < 2; ++ks) {
            bf16x8 aF[4], bF[4];
            #pragma unroll
            for (int mi = 0; mi < 4; ++mi) {
                const int rr = wr * 64 + mi * 16 + (lane & 15);
                aF[mi] = *reinterpret_cast<const bf16x8*>(
                    &As[rr * 64 + ((ks * 4 + (lane >> 4)) ^ (rr & 7)) * 8]);
            }
            #pragma unroll
            for (int ni = 0; ni < 4; ++ni) {
                const int rr = wc * 64 + ni * 16 + (lane & 15);
                bF[ni] = *reinterpret_cast<const bf16x8*>(
                    &Bs[rr * 64 + ((ks * 4 + (lane >> 4)) ^ (rr & 7)) * 8]);
            }
            #pragma unroll
            for (int mi = 0; mi < 4; ++mi)
                #pragma unroll
                for (int ni = 0; ni < 4; ++ni)
                    acc[mi][ni] = __builtin_amdgcn_mfma_f32_16x16x32_bf16(
                        aF[mi], bF[ni], acc[mi][ni], 0, 0, 0);
        }
        __syncthreads();   // all reads done before next overwrite
    }
    const int rb = mBase + wr * 64 + ((lane >> 4) << 2);
    const int cb = nBase + wc * 64 + (lane & 15);
    #pragma unroll
    for (int mi = 0; mi < 4; ++mi) {
        #pragma unroll
        for (int ni = 0; ni < 4; ++ni) {
            const int col = cb + ni * 16;
            const float badd = bias ? bias[col] : 0.f;
            #pragma unroll
            for (int i = 0; i < 4; ++i) {
                float v = acc[mi][ni][i] + badd;
                if (EPI == 2) v = 0.5f * v * (1.f + erff(v * 0.70710678118654752f));
                const long off = (long)z * cZ + (long)(rb + mi * 16 + i) * ldc + col;
                if (EPI == 1) reinterpret_cast<float*>(Cv)[off] = v;
                else          reinterpret_cast<u16*>(Cv)[off]  = f2bf(v);
            }
        }
    }
}

// ---------------- fused attention core (persistent, prefetch-pipelined) ----------------
// Grid 256 blocks x 512 threads; each block processes NL=8 consecutive l.
// QKLDS=1: 96 KB dynamic LDS (tgtS 64K + qkS 32K, both XOR-swizzled); QK reads qk
//   from LDS, so after the prefetch issue NO global load is consumed until the
//   loop-end barrier -> next-l target/qk loads fly under the whole compute phase.
// QKLDS=0 (fallback if 96 KB launch fails): 64 KB; QK reads qk from global;
//   prefetch issued after the QK loop (overlaps softmax+PV only).
// Math identical to the round-5 PASSING kernel.
#define NL 8
template<bool QKLDS>
__global__ __launch_bounds__(512) void attn_mfma(
    const u16* __restrict__ qk,        // [L][H][DM] bf16
    const float* __restrict__ target,  // [L][D][DM] f32
    const float* __restrict__ mask,    // [L][D]     f32
    u16* __restrict__ tw)              // [L][H][DM] bf16
{
    extern __shared__ u16 smem[];
    u16* tgtS = smem;                  // 32K elems (64 KB)
    u16* qkS  = smem + D * DM;         // 16K elems (32 KB), QKLDS only

    const int t = threadIdx.x, lane = t & 63, w = t >> 6;
    const int g = lane >> 4, hm = lane & 15;
    const int l0 = blockIdx.x * NL;

    float4 pf[16];
    u16x8  qf[4];
    {
        const float* tl = target + (long)l0 * (D * DM);
        #pragma unroll
        for (int it = 0; it < 16; ++it)
            pf[it] = reinterpret_cast<const float4*>(tl)[it * 512 + t];
        if (QKLDS) {
            const u16* ql = qk + (long)l0 * (H * DM);
            #pragma unroll
            for (int it = 0; it < 4; ++it)
                qf[it] = reinterpret_cast<const u16x8*>(ql)[it * 512 + t];
        }
    }

    for (int li = 0; li < NL; ++li) {
        const int l = l0 + li;
        // ---- write staged tiles into LDS (swizzled, round-5-proven layout) ----
        #pragma unroll
        for (int it = 0; it < 16; ++it) {
            const int i = it * 512 + t;
            const int d = i >> 8, mm = (i & 255) * 4, cc = mm ^ ((d & 15) << 3);
            u16x4 o = { f2bf(pf[it].x), f2bf(pf[it].y), f2bf(pf[it].z), f2bf(pf[it].w) };
            *reinterpret_cast<u16x4*>(&tgtS[d * DM + cc]) = o;
        }
        if (QKLDS) {
            #pragma unroll
            for (int it = 0; it < 4; ++it) {
                const int i = it * 512 + t;                 // 8-elem granule index
                const int h = i >> 7, mm = (i & 127) * 8, cc = mm ^ ((h & 15) << 3);
                *reinterpret_cast<u16x8*>(&qkS[h * DM + cc]) = qf[it];
            }
        }
        // mask -> regs BEFORE barrier (so no global read is consumed after prefetch)
        const float* mrow = mask + (long)l * D;
        float mk[8];
        #pragma unroll
        for (int r = 0; r < 4; ++r) { mk[r] = mrow[4 * g + r]; mk[4 + r] = mrow[16 + 4 * g + r]; }
        __syncthreads();

        // ---- issue prefetch for l+1 (variant A: before compute) ----
        if constexpr (QKLDS) {
            if (li < NL - 1) {
                const float* tn = target + (long)(l + 1) * (D * DM);
                #pragma unroll
                for (int it = 0; it < 16; ++it)
                    pf[it] = reinterpret_cast<const float4*>(tn)[it * 512 + t];
                const u16* qn = qk + (long)(l + 1) * (H * DM);
                #pragma unroll
                for (int it = 0; it < 4; ++it)
                    qf[it] = reinterpret_cast<const u16x8*>(qn)[it * 512 + t];
            }
        }

        // ---- QK: full-K scores, redundant per wave (proven fragment map) ----
        f32x4 acc0 = {0.f, 0.f, 0.f, 0.f}, acc1 = {0.f, 0.f, 0.f, 0.f};
        const u16* qrow = qk + (long)l * (H * DM) + hm * DM;
        const int swz = hm << 3;
        #pragma unroll 4
        for (int ks = 0; ks < 32; ++ks) {
            const int mcol = ks * 32 + g * 8;
            bf16x8 yf;
            if (QKLDS) yf = *reinterpret_cast<const bf16x8*>(&qkS[hm * DM + (mcol ^ swz)]);
            else       yf = *reinterpret_cast<const bf16x8*>(&qrow[mcol]);
            const bf16x8 x0 = *reinterpret_cast<const bf16x8*>(&tgtS[hm * DM + (mcol ^ swz)]);
            const bf16x8 x1 = *reinterpret_cast<const bf16x8*>(&tgtS[(16 + hm) * DM + (mcol ^ swz)]);
            acc0 = __builtin_amdgcn_mfma_f32_16x16x32_bf16(x0, yf, acc0, 0, 0, 0);
            acc1 = __builtin_amdgcn_mfma_f32_16x16x32_bf16(x1, yf, acc1, 0, 0, 0);
        }

        // ---- variant B: prefetch after the last global qk consumption ----
        if constexpr (!QKLDS) {
            if (li < NL - 1) {
                const float* tn = target + (long)(l + 1) * (D * DM);
                #pragma unroll
                for (int it = 0; it < 16; ++it)
                    pf[it] = reinterpret_cast<const float4*>(tn)[it * 512 + t];
            }
        }

        // ---- softmax over d (lane holds d = {4g+r, 16+4g+r} for h = hm) ----
        float sc[8];
        #pragma unroll
        for (int r = 0; r < 4; ++r) {
            sc[r]     = acc0[r] * 0.125f + mk[r];
            sc[4 + r] = acc1[r] * 0.125f + mk[4 + r];
        }
        float mx = sc[0];
        #pragma unroll
        for (int r = 1; r < 8; ++r) mx = fmaxf(mx, sc[r]);
        mx = fmaxf(mx, __shfl_xor(mx, 16));
        mx = fmaxf(mx, __shfl_xor(mx, 32));
        float sum = 0.f;
        #pragma unroll
        for (int r = 0; r < 8; ++r) { sc[r] = __expf(sc[r] - mx); sum += sc[r]; }
        sum += __shfl_xor(sum, 16);
        sum += __shfl_xor(sum, 32);
        const float pinv = 1.0f / sum;
        bf16x8 pfrag;
        #pragma unroll
        for (int r = 0; r < 8; ++r) pfrag[r] = (short)f2bf(sc[r] * pinv);

        // ---- PV: 8 m-tiles per wave; A = tgt^T via scalar LDS reads, B = P ----
        u16* twl = tw + (long)l * (H * DM);
        const f32x4 zero = {0.f, 0.f, 0.f, 0.f};
        #pragma unroll
        for (int i = 0; i < 8; ++i) {
            const int mg = w * 8 + i;
            const int m = mg * 16 + hm;
            bf16x8 af;
            #pragma unroll
            for (int j = 0; j < 4; ++j) {
                const int d0 = 4 * g + j;
                const int d1 = 16 + 4 * g + j;
                af[j]     = (short)tgtS[d0 * DM + (m ^ (d0 << 3))];
                af[4 + j] = (short)tgtS[d1 * DM + (m ^ (d0 << 3))];
            }
            const f32x4 c = __builtin_amdgcn_mfma_f32_16x16x32_bf16(af, pfrag, zero, 0, 0, 0);
            u16x4 o = { f2bf(c[0]), f2bf(c[1]), f2bf(c[2]), f2bf(c[3]) };
            *reinterpret_cast<u16x4*>(&twl[hm * DM + mg * 16 + 4 * g]) = o;
        }
        __syncthreads();   // drains prefetch (end of compute window); protects LDS overwrite
    }
}

// ---------------- fused residual-add + LayerNorm (2 or 3 inputs + opt col bias) ----------------
__global__ __launch_bounds__(256) void ln_fuse(
    const float* __restrict__ a, const float* __restrict__ b,
    const float* __restrict__ c, const float* __restrict__ bvec,
    const float* __restrict__ g, const float* __restrict__ be,
    float* __restrict__ o32, u16* __restrict__ o16)
{
    const int l = blockIdx.x, t = threadIdx.x;
    __shared__ float S[4], SS[4];
    __shared__ float stats[2];
    const float4 va = reinterpret_cast<const float4*>(a + (long)l * DM)[t];
    const float4 vb = reinterpret_cast<const float4*>(b + (long)l * DM)[t];
    float v[4] = { va.x + vb.x, va.y + vb.y, va.z + vb.z, va.w + vb.w };
    if (c) {
        const float4 vc = reinterpret_cast<const float4*>(c + (long)l * DM)[t];
        v[0] += vc.x; v[1] += vc.y; v[2] += vc.z; v[3] += vc.w;
    }
    if (bvec) {
        const float4 vv = reinterpret_cast<const float4*>(bvec)[t];
        v[0] += vv.x; v[1] += vv.y; v[2] += vv.z; v[3] += vv.w;
    }
    float s  = v[0] + v[1] + v[2] + v[3];
    float ss = v[0]*v[0] + v[1]*v[1] + v[2]*v[2] + v[3]*v[3];
    #pragma unroll
    for (int off = 32; off; off >>= 1) { s += __shfl_down(s, off); ss += __shfl_down(ss, off); }
    if ((t & 63) == 0) { S[t >> 6] = s; SS[t >> 6] = ss; }
    __syncthreads();
    if (t == 0) {
        const float St  = S[0] + S[1] + S[2] + S[3];
        const float SSt = SS[0] + SS[1] + SS[2] + SS[3];
        const float mu  = St * (1.f / DM);
        const float var = fmaxf(SSt * (1.f / DM) - mu * mu, 0.f);
        stats[0] = mu;
        stats[1] = rsqrtf(var + 1e-5f);
    }
    __syncthreads();
    const float mu = stats[0], rs = stats[1];
    const int c0 = t * 4;
    float ov[4];
    #pragma unroll
    for (int j = 0; j < 4; ++j) ov[j] = (v[j] - mu) * rs * g[c0 + j] + be[c0 + j];
    float4 o; o.x = ov[0]; o.y = ov[1]; o.z = ov[2]; o.w = ov[3];
    reinterpret_cast<float4*>(o32 + (long)l * DM)[t] = o;
    if (o16) {
        u16x4 q = { f2bf(ov[0]), f2bf(ov[1]), f2bf(ov[2]), f2bf(ov[3]) };
        *reinterpret_cast<u16x4*>(o16 + (long)l * DM + c0) = q;
    }
}

// ---------------- launcher ----------------
extern "C" void kernel_launch(void* const* d_in, const int* in_sizes, int n_in,
                              void* d_out, int out_size, void* d_ws, size_t ws_size,
                              hipStream_t stream)
{
    const float* src    = (const float*)d_in[0];
    const float* target = (const float*)d_in[1];
    const float* amask  = (const float*)d_in[2];
    const float* Wq = (const float*)d_in[3];
    const float* bq = (const float*)d_in[4];
    const float* Wk = (const float*)d_in[5];
    const float* Wv = (const float*)d_in[7];
    const float* bv = (const float*)d_in[8];
    const float* W1 = (const float*)d_in[9];
    const float* b1 = (const float*)d_in[10];
    const float* W2 = (const float*)d_in[11];
    const float* b2 = (const float*)d_in[12];
    const float* g1  = (const float*)d_in[13];
    const float* be1 = (const float*)d_in[14];
    const float* g2  = (const float*)d_in[15];
    const float* be2 = (const float*)d_in[16];

    // Workspace arena (peak 158 MB). qk region (30..94) is dead after attn and re-used.
    char* ws = (char*)d_ws;
    const size_t MB = (size_t)1 << 20;
    u16*   src16 = (u16*)  (ws +  0 * MB);  //  4 MB  bf16(src)
    u16*   Wk16  = (u16*)  (ws +  4 * MB);  //  2 MB  bf16(Wk)
    u16*   WqT   = (u16*)  (ws +  6 * MB);  //  2 MB  bf16(Wq^T)
    u16*   WvT   = (u16*)  (ws +  8 * MB);  //  2 MB  bf16(Wv^T)
    u16*   W1T   = (u16*)  (ws + 10 * MB);  //  8 MB  bf16(W1^T)
    u16*   W2T   = (u16*)  (ws + 18 * MB);  //  8 MB  bf16(W2^T)
    u16*   Q16   = (u16*)  (ws + 26 * MB);  //  4 MB  q = src@Wq+bq
    u16*   qk16  = (u16*)  (ws + 30 * MB);  // 64 MB  qk[l,h,m]
    u16*   Y16   = (u16*)  (ws + 30 * MB);  // 16 MB  gelu(x@W1+b1)   [aliases dead qk]
    float* Z32   = (float*)(ws + 46 * MB);  //  8 MB  Y@W2 half z=0   [aliases dead qk]
    float* Z32b  = Z32 + (long)L * DM;      //  8 MB  Y@W2 half z=1 at ws+54MB
                                            //        (= Z32 + cZ; aliases ctx32, which is
                                            //         dead after LN1. r6 BUG: this was
                                            //         declared at ws+78MB but G5 writes
                                            //         z=1 at Z32 + L*DM -> LN2 read garbage)
    float* ctx32 = (float*)(ws + 54 * MB);  //  8 MB  attention ctx   [dead after LN1]
    float* x32   = (float*)(ws + 62 * MB);  //  8 MB  LN1 out
    u16*   x16   = (u16*)  (ws + 70 * MB);  //  4 MB  bf16(x)
    u16*   tw16  = (u16*)  (ws + 94 * MB);  // 64 MB  softmax-weighted target sums

    cvt_bf<<<2048, 256, 0, stream>>>(src, src16, (L * DM) / 4);
    cvt_bf<<<1024, 256, 0, stream>>>(Wk, Wk16, (DM * DM) / 4);
    dim3 tb(32, 8);
    cvt_T<<<dim3(32, 32),  tb, 0, stream>>>(Wq, WqT, DM, DM);
    cvt_T<<<dim3(32, 32),  tb, 0, stream>>>(Wv, WvT, DM, DM);
    cvt_T<<<dim3(128, 32), tb, 0, stream>>>(W1, W1T, DM, FF);
    cvt_T<<<dim3(32, 128), tb, 0, stream>>>(W2, W2T, FF, DM);

    // G1: Q = bf16(src @ Wq + bq)
    gemm_bt<0><<<dim3(DM / 64, L / 64, 1), 256, 0, stream>>>(
        src16, DM, 0, WqT, DM, 0, Q16, DM, 0, bq, 0, DM);
    // G2 (batched over heads): qk[l,h,c] = sum_t Q[l,h,t] * Wk[c, h*64+t]
    gemm_bt<0><<<dim3(DM / 64, L / 64, H), 256, 0, stream>>>(
        Q16, DM, DH, Wk16, DM, DH, qk16, H * DM, DM, nullptr, 0, DH);

    // fused MFMA attention (variant A: 96 KB dynamic LDS; fallback B: 64 KB)
    (void)hipGetLastError();  // clear stale error
    (void)hipFuncSetAttribute(reinterpret_cast<const void*>(&attn_mfma<true>),
                              hipFuncAttributeMaxDynamicSharedMemorySize, 96 * 1024);
    attn_mfma<true><<<L / NL, 512, 96 * 1024, stream>>>(qk16, target, amask, tw16);
    if (hipGetLastError() != hipSuccess) {
        attn_mfma<false><<<L / NL, 512, 64 * 1024, stream>>>(qk16, target, amask, tw16);
    }

    // G3 (batched over heads): ctx[l, h*64+j] = sum_m tw[l,h,m] * Wv[m, h*64+j] + bv
    gemm_bt<1><<<dim3(1, L / 64, H), 256, 0, stream>>>(
        tw16, H * DM, DM, WvT, DM, (long)DH * DM, ctx32, DM, DH, bv, DH, DM);
    // x = LN(src + ctx)
    ln_fuse<<<L, 256, 0, stream>>>(src, ctx32, nullptr, nullptr, g1, be1, x32, x16);
    // G4: Y = bf16(gelu(x @ W1 + b1))   [128x128 tile, 512 blocks]
    gemm128<2><<<dim3(FF / 128, L / 128, 1), 256, 0, stream>>>(
        x16, DM, 0, W1T, DM, 0, Y16, FF, 0, b1, DM);
    // G5: Z = Y @ W2 (f32), split-K z=2 -> 256 blocks; halves at Z32 / Z32b = Z32 + L*DM
    gemm128<1><<<dim3(DM / 128, L / 128, 2), 256, 0, stream>>>(
        Y16, FF, 2048, W2T, FF, 2048, Z32, DM, (long)L * DM, nullptr, 2048);
    // out = LN(x + Za + Zb + b2)
    ln_fuse<<<L, 256, 0, stream>>>(x32, Z32, Z32b, b2, g2, be2, (float*)d_out, nullptr);
}